// Round 4
// baseline (203.471 us; speedup 1.0000x reference)
//
#include <hip/hip_runtime.h>

// LNCC multi-scale loss, fp32, (4,1,144,144,144) -> scalar.
// Scales A(K=9,ST=2) and B(K=18,ST=4) touch only EVEN coords (stride &
// dilation even) -> on the even-grid (72x72 per plane) they are plain box
// filters. big1 stages each (b,z) plane's even-grid in LDS and emits fused
// X+Y sums directly (no pass-1 intermediate in HBM). Scale C (K=36,ST=9)
// keeps the separable 3-pass path, merged into the same launches.

constexpr int BATCH = 4;
constexpr int DIM   = 144;
constexpr int NROWS = BATCH * DIM * DIM;   // 82944
constexpr float EPS = 1e-5f;

constexpr int N1C = NROWS * 9;             //   746,496  (C X-pass out)
constexpr int N2A = BATCH * DIM * 64 * 64; // 2,359,296
constexpr int N2B = BATCH * DIM * 28 * 28; //   451,584
constexpr int N2C = BATCH * DIM * 9 * 9;   //    46,656

__global__ void k_init_out(float* out) {
    if (threadIdx.x == 0 && blockIdx.x == 0) out[0] = 4.0f;
}

// ======================= shared device helpers ==============================

__device__ __forceinline__ float lncc_val(const float s[5], float inv_numel) {
    float cross = s[4] - s[0] * s[1] * inv_numel;
    float ivar  = s[2] - s[0] * s[0] * inv_numel;
    float tvar  = s[3] - s[1] * s[1] * inv_numel;
    return (cross * cross) / (ivar * tvar + EPS);
}

__device__ __forceinline__ void block_reduce_atomic(float acc, float factor, float* out) {
    #pragma unroll
    for (int off = 32; off > 0; off >>= 1) acc += __shfl_down(acc, off, 64);
    __shared__ float sm[4];
    int lane = threadIdx.x & 63, wid = threadIdx.x >> 6;
    if (lane == 0) sm[wid] = acc;
    __syncthreads();
    if (threadIdx.x == 0)
        atomicAdd(out, -factor * (sm[0] + sm[1] + sm[2] + sm[3]));
}

// ---- pass2 direct body with tap-split (C: Y-pass) --------------------------
template<int K, int ST, int OUT, int TS>
__device__ __forceinline__ void k2d_body(int tid, const float* __restrict__ in,
                                         float* __restrict__ out, int n1, int n2)
{
    const int total = BATCH * DIM * OUT * OUT * TS;
    if (tid >= total) return;
    int sp   = tid % TS;
    int rest = tid / TS;
    int xo = rest % OUT;
    int yo = (rest / OUT) % OUT;
    int bz = rest / (OUT * OUT);
    const float* base = in + (size_t)bz * DIM * OUT + xo;

    float s[5] = {0.f, 0.f, 0.f, 0.f, 0.f};
    #pragma unroll
    for (int j = 0; j < K; ++j) {
        if ((j % TS) == sp) {
            int y = ST * yo + 2 * j;
            #pragma unroll
            for (int q = 0; q < 5; ++q) s[q] += base[(size_t)q * n1 + y * OUT];
        }
    }
    if (TS > 1) {
        #pragma unroll
        for (int off = 1; off < TS; off <<= 1) {
            #pragma unroll
            for (int q = 0; q < 5; ++q) s[q] += __shfl_xor(s[q], off, 64);
        }
    }
    if (sp == 0) {
        float* ob = out + (size_t)bz * OUT * OUT + yo * OUT + xo;
        #pragma unroll
        for (int q = 0; q < 5; ++q) ob[(size_t)q * n2] = s[q];
    }
}

// ---- pass3 sliding body + LNCC (A: Z-pass) ---------------------------------
template<int K, int ST, int OUT, int CHUNK>
__device__ __forceinline__ void k3s_body(int tid, const float* __restrict__ in,
                                         float* __restrict__ out, int n2,
                                         float inv_numel, float factor)
{
    constexpr int NCH = OUT / CHUNK;
    const int total = BATCH * NCH * OUT * OUT;
    float acc = 0.f;
    if (tid < total) {
        int xo = tid % OUT;
        int yo = (tid / OUT) % OUT;
        int ch = (tid / (OUT * OUT)) % NCH;
        int b  = tid / (OUT * OUT * NCH);
        const int zo0 = ch * CHUNK;
        const int OO = OUT * OUT;
        const float* base = in + (size_t)b * DIM * OO + yo * OUT + xo;

        float s[5] = {0.f, 0.f, 0.f, 0.f, 0.f};
        #pragma unroll
        for (int j = 0; j < K; ++j) {
            int z = ST * zo0 + 2 * j;
            #pragma unroll
            for (int q = 0; q < 5; ++q) s[q] += base[(size_t)q * n2 + z * OO];
        }
        acc += lncc_val(s, inv_numel);
        #pragma unroll
        for (int i = 1; i < CHUNK; ++i) {
            int zold = ST * (zo0 + i - 1);
            int znew = zold + 2 * K;
            #pragma unroll
            for (int q = 0; q < 5; ++q)
                s[q] += base[(size_t)q * n2 + znew * OO]
                      - base[(size_t)q * n2 + zold * OO];
            acc += lncc_val(s, inv_numel);
        }
    }
    block_reduce_atomic(acc, factor, out);
}

// ---- pass3 direct body + tap-split + LNCC (B,C: Z-pass) --------------------
template<int K, int ST, int OUT, int TS>
__device__ __forceinline__ void k3d_body(int tid, const float* __restrict__ in,
                                         float* __restrict__ out, int n2,
                                         float inv_numel, float factor)
{
    const int total = BATCH * OUT * OUT * OUT * TS;
    float acc = 0.f;
    if (tid < total) {
        int sp   = tid % TS;
        int rest = tid / TS;
        int xo = rest % OUT;
        int yo = (rest / OUT) % OUT;
        int zo = (rest / (OUT * OUT)) % OUT;
        int b  = rest / (OUT * OUT * OUT);
        const int OO = OUT * OUT;
        const float* base = in + (size_t)b * DIM * OO + yo * OUT + xo;

        float s[5] = {0.f, 0.f, 0.f, 0.f, 0.f};
        #pragma unroll
        for (int j = 0; j < K; ++j) {
            if ((j % TS) == sp) {
                int z = ST * zo + 2 * j;
                #pragma unroll
                for (int q = 0; q < 5; ++q) s[q] += base[(size_t)q * n2 + z * OO];
            }
        }
        if (TS > 1) {
            #pragma unroll
            for (int off = 1; off < TS; off <<= 1) {
                #pragma unroll
                for (int q = 0; q < 5; ++q) s[q] += __shfl_xor(s[q], off, 64);
            }
        }
        if (sp == 0) acc = lncc_val(s, inv_numel);
    }
    block_reduce_atomic(acc, factor, out);
}

// ======================= big1: fused XY (A,B) + X (C) =======================
// Block roles per (b,z) plane: role 0 = fused even-grid XY for scales A,B;
// roles 1..9 = scale-C X-pass on 16 rows each.
// LDS: role 0 uses le[2][72][73] (42 KB) + sa[72][16][5] (23 KB) = 65,088 B.

constexpr int SMEM_FLOATS = 2 * 72 * 73 + 72 * 16 * 5;   // 16272 (65,088 B)

__device__ void kxy_body(int bz, const float* __restrict__ in,
                         const float* __restrict__ tg,
                         float* __restrict__ b2a, float* __restrict__ b2b,
                         float* smem)
{
    float* le = smem;                       // [2][72][73] even-grid in/tg
    float* sa = smem + 2 * 72 * 73;         // A: [72][16][5] / B: [72][14][5]
    const int t = threadIdx.x;
    const float* gin = in + (size_t)bz * DIM * DIM;
    const float* gtg = tg + (size_t)bz * DIM * DIM;

    for (int i = t; i < 72 * 72; i += 256) {
        int yp = i / 72, xp = i % 72;
        int g = yp * 2 * DIM + xp * 2;
        le[yp * 73 + xp]            = gin[g];
        le[72 * 73 + yp * 73 + xp]  = gtg[g];
    }
    __syncthreads();

    // ---- scale A: 9x9 box, stride 1 on even-grid; 4 xo-chunks of 16 ----
    #pragma unroll 1
    for (int c = 0; c < 4; ++c) {
        const int xo0 = c * 16;
        for (int i = t; i < 72 * 16; i += 256) {
            int yp = i / 16, dx = i % 16;
            const float* pa = &le[yp * 73 + xo0 + dx];
            const float* pb = &le[72 * 73 + yp * 73 + xo0 + dx];
            float s0 = 0.f, s1 = 0.f, s2 = 0.f, s3 = 0.f, s4 = 0.f;
            #pragma unroll
            for (int j = 0; j < 9; ++j) {
                float a = pa[j], b = pb[j];
                s0 += a; s1 += b; s2 += a * a; s3 += b * b; s4 += a * b;
            }
            float* d = &sa[(yp * 16 + dx) * 5];
            d[0] = s0; d[1] = s1; d[2] = s2; d[3] = s3; d[4] = s4;
        }
        __syncthreads();
        for (int i = t; i < 64 * 16; i += 256) {
            int yo = i / 16, dx = i % 16;
            float s[5] = {0.f, 0.f, 0.f, 0.f, 0.f};
            #pragma unroll
            for (int j = 0; j < 9; ++j) {
                const float* p = &sa[((yo + j) * 16 + dx) * 5];
                s[0] += p[0]; s[1] += p[1]; s[2] += p[2]; s[3] += p[3]; s[4] += p[4];
            }
            int o = (bz * 64 + yo) * 64 + xo0 + dx;
            #pragma unroll
            for (int q = 0; q < 5; ++q) b2a[(size_t)q * N2A + o] = s[q];
        }
        __syncthreads();
    }

    // ---- scale B: 18x18 box, stride 2 on even-grid; 2 xo-chunks of 14 ----
    #pragma unroll 1
    for (int c = 0; c < 2; ++c) {
        const int xo0 = c * 14;
        for (int i = t; i < 72 * 14; i += 256) {
            int yp = i / 14, dx = i % 14;
            int xp0 = (xo0 + dx) * 2;
            const float* pa = &le[yp * 73 + xp0];
            const float* pb = &le[72 * 73 + yp * 73 + xp0];
            float s0 = 0.f, s1 = 0.f, s2 = 0.f, s3 = 0.f, s4 = 0.f;
            #pragma unroll
            for (int j = 0; j < 18; ++j) {
                float a = pa[j], b = pb[j];
                s0 += a; s1 += b; s2 += a * a; s3 += b * b; s4 += a * b;
            }
            float* d = &sa[(yp * 14 + dx) * 5];
            d[0] = s0; d[1] = s1; d[2] = s2; d[3] = s3; d[4] = s4;
        }
        __syncthreads();
        for (int i = t; i < 28 * 14; i += 256) {
            int yo = i / 14, dx = i % 14;
            float s[5] = {0.f, 0.f, 0.f, 0.f, 0.f};
            #pragma unroll
            for (int j = 0; j < 18; ++j) {
                const float* p = &sa[((yo * 2 + j) * 14 + dx) * 5];
                s[0] += p[0]; s[1] += p[1]; s[2] += p[2]; s[3] += p[3]; s[4] += p[4];
            }
            int o = (bz * 28 + yo) * 28 + xo0 + dx;
            #pragma unroll
            for (int q = 0; q < 5; ++q) b2b[(size_t)q * N2B + o] = s[q];
        }
        __syncthreads();
    }
}

__device__ void cx_body(int bz, int r, const float* __restrict__ in,
                        const float* __restrict__ tg,
                        float* __restrict__ b1c, float* smem)
{
    float* la = smem;                 // [16][145]
    float* lb = smem + 16 * 145;
    const int t = threadIdx.x;
    const int row0 = bz * DIM + r * 16;
    const float* gin = in + (size_t)row0 * DIM;
    const float* gtg = tg + (size_t)row0 * DIM;
    for (int i = t; i < 16 * DIM; i += 256) {
        int rr = i / DIM, cc = i % DIM;
        la[rr * 145 + cc] = gin[i];
        lb[rr * 145 + cc] = gtg[i];
    }
    __syncthreads();
    int rr = t >> 4, xo = t & 15;
    if (xo < 9) {
        const float* pa = &la[rr * 145 + xo * 9];
        const float* pb = &lb[rr * 145 + xo * 9];
        float s0 = 0.f, s1 = 0.f, s2 = 0.f, s3 = 0.f, s4 = 0.f;
        #pragma unroll
        for (int j = 0; j < 36; ++j) {
            float a = pa[2 * j], b = pb[2 * j];
            s0 += a; s1 += b; s2 += a * a; s3 += b * b; s4 += a * b;
        }
        int o = (row0 + rr) * 9 + xo;
        b1c[o] = s0; b1c[N1C + o] = s1; b1c[2 * N1C + o] = s2;
        b1c[3 * N1C + o] = s3; b1c[4 * N1C + o] = s4;
    }
}

__global__ __launch_bounds__(256) void k_big1(const float* __restrict__ in,
                                              const float* __restrict__ tg,
                                              float* __restrict__ b2a,
                                              float* __restrict__ b2b,
                                              float* __restrict__ b1c)
{
    __shared__ float smem[SMEM_FLOATS];
    int plane = blockIdx.x / 10;
    int role  = blockIdx.x % 10;
    if (role == 0) kxy_body(plane, in, tg, b2a, b2b, smem);
    else           cx_body(plane, role - 1, in, tg, b1c, smem);
}

// ======================= mid: A-Z + B-Z + C-Y ================================

constexpr int B_K3A = (BATCH * (64 / 8) * 64 * 64) / 256;         // 512
constexpr int B_K3B = (BATCH * 28 * 28 * 28 * 8) / 256;           // 2744
constexpr int B_K2C = (BATCH * DIM * 9 * 9 * 8) / 256;            // 1458
constexpr int B_K3C = (BATCH * 9 * 9 * 9 * 16 + 255) / 256;       // 183

__global__ __launch_bounds__(256) void k_mid(const float* __restrict__ b2a,
                                             const float* __restrict__ b2b,
                                             const float* __restrict__ b1c,
                                             float* __restrict__ b2c,
                                             float* __restrict__ out)
{
    int blk = blockIdx.x;
    if (blk < B_K3A) {
        k3s_body<9, 2, 64, 8>(blk * 256 + threadIdx.x, b2a, out, N2A,
                              1.0f / 729.0f, 0.1f / 262144.0f);
    } else if (blk < B_K3A + B_K3B) {
        k3d_body<18, 4, 28, 8>((blk - B_K3A) * 256 + threadIdx.x, b2b, out, N2B,
                               1.0f / 5832.0f, 0.3f / 21952.0f);
    } else {
        k2d_body<36, 9, 9, 8>((blk - B_K3A - B_K3B) * 256 + threadIdx.x,
                              b1c, b2c, N1C, N2C);
    }
}

__global__ __launch_bounds__(256) void k_final(const float* __restrict__ b2c,
                                               float* __restrict__ out)
{
    k3d_body<36, 9, 9, 16>(blockIdx.x * 256 + threadIdx.x, b2c, out, N2C,
                           1.0f / 46656.0f, 0.6f / 729.0f);
}

// ============================================================================
extern "C" void kernel_launch(void* const* d_in, const int* in_sizes, int n_in,
                              void* d_out, int out_size, void* d_ws, size_t ws_size,
                              hipStream_t stream) {
    const float* input  = (const float*)d_in[0];
    const float* target = (const float*)d_in[1];
    float* out = (float*)d_out;

    // workspace: b2a (5*N2A) | b2b (5*N2B) | b1c (5*N1C) | b2c (5*N2C) = 72 MB
    float* b2a = (float*)d_ws;
    float* b2b = b2a + (size_t)5 * N2A;
    float* b1c = b2b + (size_t)5 * N2B;
    float* b2c = b1c + (size_t)5 * N1C;

    k_init_out<<<1, 64, 0, stream>>>(out);
    k_big1<<<BATCH * DIM * 10, 256, 0, stream>>>(input, target, b2a, b2b, b1c);
    k_mid<<<B_K3A + B_K3B + B_K2C, 256, 0, stream>>>(b2a, b2b, b1c, b2c, out);
    k_final<<<B_K3C, 256, 0, stream>>>(b2c, out);
}

// Round 5
// 125.799 us; speedup vs baseline: 1.6174x; 1.6174x over previous
//
#include <hip/hip_runtime.h>

// LNCC multi-scale loss, fp32, (4,1,144,144,144) -> scalar.
// Scales A(K=9,ST=2) and B(K=18,ST=4): all taps hit even coords in all three
// dims -> both live on the even-grid volume (4 x 72 x 72 x 72).
//   A = plain 9^3 box, stride 1, on even grid (out 64^3)
//   B = plain 18^3 box, stride 2, on even grid (out 28^3)
//     and an 18-window = two 9-windows => B's XY sums are 4 adds over A's XY.
// Scale C (K=36, ST=9, mixed parity) keeps the separable 3-pass path.
// k1: A-XY (per even-z plane, x-chunked) + C-X   [one input sweep]
// k2: A-Z+LNCC (sliding) + B-XY-from-A + C-Y
// k3: B-Z+LNCC + C-Z+LNCC

constexpr int BATCH = 4;
constexpr int DIM   = 144;
constexpr int NROWS = BATCH * DIM * DIM;        // 82944
constexpr float EPS = 1e-5f;

constexpr int N1C  = NROWS * 9;                 //   746,496 (C X-out)
constexpr int N2Ae = BATCH * 72 * 64 * 64;      // 1,179,648 (A XY-out, even-z)
constexpr int N2Be = BATCH * 72 * 28 * 28;      //   225,792 (B XY-out, even-z)
constexpr int N2C  = BATCH * DIM * 9 * 9;       //    46,656 (C Y-out)

__global__ void k_init_out(float* out) {
    if (threadIdx.x == 0 && blockIdx.x == 0) out[0] = 4.0f;
}

// ======================= shared device helpers ==============================

__device__ __forceinline__ float lncc_val(const float s[5], float inv_numel) {
    float cross = s[4] - s[0] * s[1] * inv_numel;
    float ivar  = s[2] - s[0] * s[0] * inv_numel;
    float tvar  = s[3] - s[1] * s[1] * inv_numel;
    return (cross * cross) / (ivar * tvar + EPS);
}

__device__ __forceinline__ void block_reduce_atomic(float acc, float factor, float* out) {
    #pragma unroll
    for (int off = 32; off > 0; off >>= 1) acc += __shfl_down(acc, off, 64);
    __shared__ float sm[4];
    int lane = threadIdx.x & 63, wid = threadIdx.x >> 6;
    if (lane == 0) sm[wid] = acc;
    __syncthreads();
    if (threadIdx.x == 0)
        atomicAdd(out, -factor * (sm[0] + sm[1] + sm[2] + sm[3]));
}

// ======================= k1 bodies ==========================================
// role A: fused XY for scale A on one even-z plane, one x-chunk of 16 outputs.
// LDS: ea[72][25] + eb[72][25] + xs[5][72][16] = 9360 floats (37.4 KB)

__device__ void aXY_body(int blk, const float* __restrict__ in,
                         const float* __restrict__ tg,
                         float* __restrict__ b2a, float* smem)
{
    const int p  = blk >> 2;          // 0..287  (b*72 + ez)
    const int c  = blk & 3;           // x-chunk
    const int b  = p / 72;
    const int ez = p % 72;
    const int xo0 = c * 16;
    const size_t gplane = (size_t)(b * DIM + 2 * ez) * (DIM * DIM);
    const int t = threadIdx.x;

    float* ea = smem;                  // [72][25]
    float* eb = smem + 1800;           // [72][25]
    float* xs = smem + 3600;           // [5][72][16]

    // stage even-grid strip: 72 even-y rows x 24 even-x cols
    for (int i = t; i < 72 * 24; i += 256) {
        int ey = i / 24, e = i % 24;
        size_t g = gplane + (size_t)(2 * ey) * DIM + 2 * (xo0 + e);
        ea[ey * 25 + e] = in[g];
        eb[ey * 25 + e] = tg[g];
    }
    __syncthreads();

    // X: 9-tap sums for 72 rows x 16 cols, 5 quantities
    for (int i = t; i < 72 * 16; i += 256) {
        int yp = i / 16, dx = i % 16;
        const float* pa = &ea[yp * 25 + dx];
        const float* pb = &eb[yp * 25 + dx];
        float s0 = 0.f, s1 = 0.f, s2 = 0.f, s3 = 0.f, s4 = 0.f;
        #pragma unroll
        for (int j = 0; j < 9; ++j) {
            float a = pa[j], bb = pb[j];
            s0 += a; s1 += bb; s2 += a * a; s3 += bb * bb; s4 += a * bb;
        }
        int o = yp * 16 + dx;
        xs[o] = s0; xs[1152 + o] = s1; xs[2 * 1152 + o] = s2;
        xs[3 * 1152 + o] = s3; xs[4 * 1152 + o] = s4;
    }
    __syncthreads();

    // Y: 9-tap sums over xs rows -> 64 x 16 outputs
    for (int i = t; i < 64 * 16; i += 256) {
        int yo = i / 16, dx = i % 16;
        float s[5] = {0.f, 0.f, 0.f, 0.f, 0.f};
        #pragma unroll
        for (int j = 0; j < 9; ++j) {
            int o = (yo + j) * 16 + dx;
            #pragma unroll
            for (int q = 0; q < 5; ++q) s[q] += xs[q * 1152 + o];
        }
        size_t o = ((size_t)p * 64 + yo) * 64 + xo0 + dx;
        #pragma unroll
        for (int q = 0; q < 5; ++q) b2a[(size_t)q * N2Ae + o] = s[q];
    }
}

// role C: scale-C X-pass on 16 consecutive rows. LDS: 2*16*145 = 4640 floats.
__device__ void cX_body(int blk, const float* __restrict__ in,
                        const float* __restrict__ tg,
                        float* __restrict__ b1c, float* smem)
{
    float* la = smem;                 // [16][145]
    float* lb = smem + 16 * 145;
    const int t = threadIdx.x;
    const int row0 = blk * 16;
    const float* gin = in + (size_t)row0 * DIM;
    const float* gtg = tg + (size_t)row0 * DIM;
    for (int i = t; i < 16 * DIM; i += 256) {
        int rr = i / DIM, cc = i % DIM;
        la[rr * 145 + cc] = gin[i];
        lb[rr * 145 + cc] = gtg[i];
    }
    __syncthreads();
    int rr = t >> 4, xo = t & 15;
    if (xo < 9) {
        const float* pa = &la[rr * 145 + xo * 9];
        const float* pb = &lb[rr * 145 + xo * 9];
        float s0 = 0.f, s1 = 0.f, s2 = 0.f, s3 = 0.f, s4 = 0.f;
        #pragma unroll
        for (int j = 0; j < 36; ++j) {
            float a = pa[2 * j], b = pb[2 * j];
            s0 += a; s1 += b; s2 += a * a; s3 += b * b; s4 += a * b;
        }
        int o = (row0 + rr) * 9 + xo;
        b1c[o] = s0; b1c[N1C + o] = s1; b1c[2 * N1C + o] = s2;
        b1c[3 * N1C + o] = s3; b1c[4 * N1C + o] = s4;
    }
}

constexpr int B_AXY = BATCH * 72 * 4;        // 1152
constexpr int B_CX  = NROWS / 16;            // 5184

__global__ __launch_bounds__(256) void k1(const float* __restrict__ in,
                                          const float* __restrict__ tg,
                                          float* __restrict__ b2a,
                                          float* __restrict__ b1c)
{
    __shared__ float smem[9360];
    int blk = blockIdx.x;
    if (blk < B_AXY) aXY_body(blk, in, tg, b2a, smem);
    else             cX_body(blk - B_AXY, in, tg, b1c, smem);
}

// ======================= k2 bodies ==========================================

// A: Z box-sum (9 consecutive even-z planes, stride 1) + LNCC, sliding CHUNK=8
__device__ __forceinline__ void aZ_body(int tid, const float* __restrict__ b2a,
                                        float* __restrict__ out)
{
    const int total = BATCH * 8 * 64 * 64;           // 131072
    float acc = 0.f;
    if (tid < total) {
        int xo = tid & 63;
        int yo = (tid >> 6) & 63;
        int ch = (tid >> 12) & 7;
        int b  = tid >> 15;
        const int zo0 = ch * 8;
        const int OO = 64 * 64;
        const float* base = b2a + (size_t)b * 72 * OO + yo * 64 + xo;

        float s[5] = {0.f, 0.f, 0.f, 0.f, 0.f};
        #pragma unroll
        for (int j = 0; j < 9; ++j) {
            #pragma unroll
            for (int q = 0; q < 5; ++q)
                s[q] += base[(size_t)q * N2Ae + (zo0 + j) * OO];
        }
        acc += lncc_val(s, 1.0f / 729.0f);
        #pragma unroll
        for (int i = 1; i < 8; ++i) {
            #pragma unroll
            for (int q = 0; q < 5; ++q)
                s[q] += base[(size_t)q * N2Ae + (zo0 + i + 8) * OO]
                      - base[(size_t)q * N2Ae + (zo0 + i - 1) * OO];
            acc += lncc_val(s, 1.0f / 729.0f);
        }
    }
    block_reduce_atomic(acc, 0.1f / 262144.0f, out);
}

// B XY from A's XY: 18x18 window = four 9x9 windows
__device__ __forceinline__ void bXY_body(int tid, const float* __restrict__ b2a,
                                         float* __restrict__ b2b)
{
    const int total = BATCH * 72 * 28 * 28;          // 225792
    if (tid >= total) return;
    int xo = tid % 28;
    int yo = (tid / 28) % 28;
    int p  = tid / 784;
    const float* ib = b2a + (size_t)p * 4096;
    float* ob = b2b + (size_t)p * 784 + yo * 28 + xo;
    int r0 = (2 * yo) * 64 + 2 * xo;
    #pragma unroll
    for (int q = 0; q < 5; ++q) {
        const float* pq = ib + (size_t)q * N2Ae;
        ob[(size_t)q * N2Be] =
            pq[r0] + pq[r0 + 9] + pq[r0 + 9 * 64] + pq[r0 + 9 * 64 + 9];
    }
}

// C: Y-pass direct, tap-split TS=8 (reads b1c, writes b2c)
__device__ __forceinline__ void cY_body(int tid, const float* __restrict__ b1c,
                                        float* __restrict__ b2c)
{
    const int total = BATCH * DIM * 9 * 9 * 8;
    if (tid >= total) return;
    int sp   = tid & 7;
    int rest = tid >> 3;
    int xo = rest % 9;
    int yo = (rest / 9) % 9;
    int bz = rest / 81;
    const float* base = b1c + (size_t)bz * DIM * 9 + xo;

    float s[5] = {0.f, 0.f, 0.f, 0.f, 0.f};
    #pragma unroll
    for (int j = 0; j < 36; ++j) {
        if ((j & 7) == sp) {
            int y = 9 * yo + 2 * j;
            #pragma unroll
            for (int q = 0; q < 5; ++q) s[q] += base[(size_t)q * N1C + y * 9];
        }
    }
    #pragma unroll
    for (int off = 1; off < 8; off <<= 1) {
        #pragma unroll
        for (int q = 0; q < 5; ++q) s[q] += __shfl_xor(s[q], off, 64);
    }
    if (sp == 0) {
        float* ob = b2c + (size_t)bz * 81 + yo * 9 + xo;
        #pragma unroll
        for (int q = 0; q < 5; ++q) ob[(size_t)q * N2C] = s[q];
    }
}

constexpr int B_AZ  = (BATCH * 8 * 64 * 64) / 256;   // 512
constexpr int B_BXY = (BATCH * 72 * 28 * 28) / 256;  // 882
constexpr int B_CY  = (BATCH * DIM * 9 * 9 * 8) / 256; // 1458

__global__ __launch_bounds__(256) void k2(const float* __restrict__ b2a,
                                          const float* __restrict__ b1c,
                                          float* __restrict__ b2b,
                                          float* __restrict__ b2c,
                                          float* __restrict__ out)
{
    int blk = blockIdx.x;
    if (blk < B_AZ)              aZ_body(blk * 256 + threadIdx.x, b2a, out);
    else if (blk < B_AZ + B_BXY) bXY_body((blk - B_AZ) * 256 + threadIdx.x, b2a, b2b);
    else                         cY_body((blk - B_AZ - B_BXY) * 256 + threadIdx.x, b1c, b2c);
}

// ======================= k3 bodies ==========================================

// B: Z box-sum (18 consecutive even-z planes, stride 2 base) + LNCC, TS=8
__device__ __forceinline__ void bZ_body(int tid, const float* __restrict__ b2b,
                                        float* __restrict__ out)
{
    const int total = BATCH * 28 * 28 * 28 * 8;      // 702464 (mult of 64)
    float acc = 0.f;
    if (tid < total) {
        int sp   = tid & 7;
        int rest = tid >> 3;
        int xo = rest % 28;
        int yo = (rest / 28) % 28;
        int zo = (rest / 784) % 28;
        int b  = rest / 21952;
        const int OO = 784;
        const float* base = b2b + (size_t)b * 72 * OO + yo * 28 + xo;

        float s[5] = {0.f, 0.f, 0.f, 0.f, 0.f};
        #pragma unroll
        for (int j = 0; j < 18; ++j) {
            if ((j & 7) == sp) {
                #pragma unroll
                for (int q = 0; q < 5; ++q)
                    s[q] += base[(size_t)q * N2Be + (2 * zo + j) * OO];
            }
        }
        #pragma unroll
        for (int off = 1; off < 8; off <<= 1) {
            #pragma unroll
            for (int q = 0; q < 5; ++q) s[q] += __shfl_xor(s[q], off, 64);
        }
        if (sp == 0) acc = lncc_val(s, 1.0f / 5832.0f);
    }
    block_reduce_atomic(acc, 0.3f / 21952.0f, out);
}

// C: Z-pass + LNCC, tap-split TS=16 (original z space, both parities)
__device__ __forceinline__ void cZ_body(int tid, const float* __restrict__ b2c,
                                        float* __restrict__ out)
{
    const int total = BATCH * 9 * 9 * 9 * 16;        // 46656 (mult of 64)
    float acc = 0.f;
    if (tid < total) {
        int sp   = tid & 15;
        int rest = tid >> 4;
        int xo = rest % 9;
        int yo = (rest / 9) % 9;
        int zo = (rest / 81) % 9;
        int b  = rest / 729;
        const int OO = 81;
        const float* base = b2c + (size_t)b * DIM * OO + yo * 9 + xo;

        float s[5] = {0.f, 0.f, 0.f, 0.f, 0.f};
        #pragma unroll
        for (int j = 0; j < 36; ++j) {
            if ((j & 15) == sp) {
                int z = 9 * zo + 2 * j;
                #pragma unroll
                for (int q = 0; q < 5; ++q) s[q] += base[(size_t)q * N2C + z * OO];
            }
        }
        #pragma unroll
        for (int off = 1; off < 16; off <<= 1) {
            #pragma unroll
            for (int q = 0; q < 5; ++q) s[q] += __shfl_xor(s[q], off, 64);
        }
        if (sp == 0) acc = lncc_val(s, 1.0f / 46656.0f);
    }
    block_reduce_atomic(acc, 0.6f / 729.0f, out);
}

constexpr int B_BZ = (BATCH * 28 * 28 * 28 * 8) / 256;   // 2744
constexpr int B_CZ = (BATCH * 9 * 9 * 9 * 16 + 255) / 256; // 183

__global__ __launch_bounds__(256) void k3(const float* __restrict__ b2b,
                                          const float* __restrict__ b2c,
                                          float* __restrict__ out)
{
    int blk = blockIdx.x;
    if (blk < B_BZ) bZ_body(blk * 256 + threadIdx.x, b2b, out);
    else            cZ_body((blk - B_BZ) * 256 + threadIdx.x, b2c, out);
}

// ============================================================================
extern "C" void kernel_launch(void* const* d_in, const int* in_sizes, int n_in,
                              void* d_out, int out_size, void* d_ws, size_t ws_size,
                              hipStream_t stream) {
    const float* input  = (const float*)d_in[0];
    const float* target = (const float*)d_in[1];
    float* out = (float*)d_out;

    // workspace: b2a 23.6MB | b1c 14.9MB | b2b 4.5MB | b2c 0.93MB  (~44MB)
    float* b2a = (float*)d_ws;
    float* b1c = b2a + (size_t)5 * N2Ae;
    float* b2b = b1c + (size_t)5 * N1C;
    float* b2c = b2b + (size_t)5 * N2Be;

    k_init_out<<<1, 64, 0, stream>>>(out);
    k1<<<B_AXY + B_CX, 256, 0, stream>>>(input, target, b2a, b1c);
    k2<<<B_AZ + B_BXY + B_CY, 256, 0, stream>>>(b2a, b1c, b2b, b2c, out);
    k3<<<B_BZ + B_CZ, 256, 0, stream>>>(b2b, b2c, out);
}

// Round 6
// 118.197 us; speedup vs baseline: 1.7215x; 1.0643x over previous
//
#include <hip/hip_runtime.h>

// LNCC multi-scale loss, fp32, (4,1,144,144,144) -> scalar.
// A(K=9,ST=2), B(K=18,ST=4): all taps on even coords -> even-grid volume.
//   A = 9^3 box stride 1 on even grid; B3 = sum over {0,9}^3 offsets of A's
//   9^3 windows => B's Z-pass reads A's XY-sums (b2a) directly.
// C(K=36,ST=9): separable 3-pass (X staged in LDS, Y/Z tap-split direct).
// k1: A-XY (global-tap X + sliding Y) + C-X + out init   [one input sweep]
// k2: B-Z+LNCC (direct from b2a) + A-Z+LNCC (sliding) + C-Y
// k3: C-Z+LNCC

constexpr int BATCH = 4;
constexpr int DIM   = 144;
constexpr int NROWS = BATCH * DIM * DIM;        // 82944
constexpr float EPS = 1e-5f;

constexpr int N1C  = NROWS * 9;                 //   746,496 (C X-out)
constexpr int N2Ae = BATCH * 72 * 64 * 64;      // 1,179,648 (A XY-out)
constexpr int N2C  = BATCH * DIM * 9 * 9;       //    46,656 (C Y-out)

// ======================= shared device helpers ==============================

__device__ __forceinline__ float lncc_val(const float s[5], float inv_numel) {
    float cross = s[4] - s[0] * s[1] * inv_numel;
    float ivar  = s[2] - s[0] * s[0] * inv_numel;
    float tvar  = s[3] - s[1] * s[1] * inv_numel;
    return (cross * cross) / (ivar * tvar + EPS);
}

__device__ __forceinline__ void block_reduce_atomic(float acc, float factor, float* out) {
    #pragma unroll
    for (int off = 32; off > 0; off >>= 1) acc += __shfl_down(acc, off, 64);
    __shared__ float sm[4];
    int lane = threadIdx.x & 63, wid = threadIdx.x >> 6;
    if (lane == 0) sm[wid] = acc;
    __syncthreads();
    if (threadIdx.x == 0)
        atomicAdd(out, -factor * (sm[0] + sm[1] + sm[2] + sm[3]));
}

// ======================= k1 bodies ==========================================
// aXY: one even-z plane, one 16-wide xo chunk. X-phase taps read global
// directly (L1/L2-hot); X-sums go to padded LDS xs[72][81]; Y-phase is a
// per-thread sliding window writing b2a coalesced (16-float runs).

__device__ void aXY_body(int blk, const float* __restrict__ in,
                         const float* __restrict__ tg,
                         float* __restrict__ b2a, float* xs)
{
    const int p  = blk >> 2;            // b*72 + ez
    const int c  = blk & 3;
    const int b  = p / 72;
    const int ez = p % 72;
    const int xo0 = c * 16;
    const size_t gpl = (size_t)(b * DIM + 2 * ez) * (DIM * DIM);
    const int t = threadIdx.x;

    // X: items (yp 0..71, dx 0..15), 9 even-x taps from global
    for (int i = t; i < 72 * 16; i += 256) {
        int yp = i >> 4, dx = i & 15;
        size_t g = gpl + (size_t)(2 * yp) * DIM + 2 * (size_t)(xo0 + dx);
        const float* ga = in + g;
        const float* gb = tg + g;
        float s0 = 0.f, s1 = 0.f, s2 = 0.f, s3 = 0.f, s4 = 0.f;
        #pragma unroll
        for (int j = 0; j < 9; ++j) {
            float a = ga[2 * j], bb = gb[2 * j];
            s0 += a; s1 += bb; s2 += a * a; s3 += bb * bb; s4 += a * bb;
        }
        float* d = &xs[yp * 81 + dx];
        d[0] = s0; d[16] = s1; d[32] = s2; d[48] = s3; d[64] = s4;
    }
    __syncthreads();

    // Y: items (ch 0..3, q 0..4, dx 0..15) = 320, sliding over 16 yo each
    for (int it = t; it < 320; it += 256) {
        int dx = it & 15;
        int q  = (it >> 4) % 5;
        int ch = it / 80;
        int yo0 = ch << 4;
        const float* xp = &xs[q * 16 + dx];
        float s = 0.f;
        #pragma unroll
        for (int j = 0; j < 9; ++j) s += xp[(yo0 + j) * 81];
        float* ob = b2a + (size_t)q * N2Ae + ((size_t)p * 64 + yo0) * 64 + xo0 + dx;
        ob[0] = s;
        #pragma unroll
        for (int i2 = 1; i2 < 16; ++i2) {
            s += xp[(yo0 + i2 + 8) * 81] - xp[(yo0 + i2 - 1) * 81];
            ob[(size_t)i2 * 64] = s;
        }
    }
}

// cX: 12 rows staged in LDS, 2-way tap-split -> 216/256 threads compute
constexpr int CXROWS = 12;

__device__ void cX_body(int blk, const float* __restrict__ in,
                        const float* __restrict__ tg,
                        float* __restrict__ b1c, float* sm)
{
    float* la = sm;                     // [12][145]
    float* lb = sm + CXROWS * 145;
    const int t = threadIdx.x;
    const int row0 = blk * CXROWS;
    const float* gin = in + (size_t)row0 * DIM;
    const float* gtg = tg + (size_t)row0 * DIM;
    for (int i = t; i < CXROWS * DIM; i += 256) {
        int rr = i / DIM, cc = i % DIM;
        la[rr * 145 + cc] = gin[i];
        lb[rr * 145 + cc] = gtg[i];
    }
    __syncthreads();
    if (t < CXROWS * 18) {
        int rr  = t / 18;
        int rem = t % 18;
        int xo = rem >> 1, sp = rem & 1;
        const float* pa = &la[rr * 145 + xo * 9 + 2 * sp];
        const float* pb = &lb[rr * 145 + xo * 9 + 2 * sp];
        float s0 = 0.f, s1 = 0.f, s2 = 0.f, s3 = 0.f, s4 = 0.f;
        #pragma unroll
        for (int jj = 0; jj < 18; ++jj) {          // taps j = sp + 2*jj
            float a = pa[4 * jj], b = pb[4 * jj];
            s0 += a; s1 += b; s2 += a * a; s3 += b * b; s4 += a * b;
        }
        s0 += __shfl_xor(s0, 1, 64);
        s1 += __shfl_xor(s1, 1, 64);
        s2 += __shfl_xor(s2, 1, 64);
        s3 += __shfl_xor(s3, 1, 64);
        s4 += __shfl_xor(s4, 1, 64);
        if (sp == 0) {
            int o = (row0 + rr) * 9 + xo;
            b1c[o] = s0; b1c[N1C + o] = s1; b1c[2 * N1C + o] = s2;
            b1c[3 * N1C + o] = s3; b1c[4 * N1C + o] = s4;
        }
    }
}

constexpr int B_AXY = BATCH * 72 * 4;        // 1152
constexpr int B_CX  = NROWS / CXROWS;        // 6912
constexpr int SM1   = 72 * 81;               // 5832 floats (23.3 KB)

__global__ __launch_bounds__(256) void k1(const float* __restrict__ in,
                                          const float* __restrict__ tg,
                                          float* __restrict__ b2a,
                                          float* __restrict__ b1c,
                                          float* __restrict__ out)
{
    __shared__ float smem[SM1];
    if (blockIdx.x == 0 && threadIdx.x == 0) out[0] = 4.0f;
    int blk = blockIdx.x;
    if (blk < B_AXY) aXY_body(blk, in, tg, b2a, smem);
    else             cX_body(blk - B_AXY, in, tg, b1c, smem);
}

// ======================= k2 bodies ==========================================

// B: Z+LNCC direct from b2a. Wave layout: lane = [sp:3][xl:3]|..,
// gid over (b, zo, yo, xh). 18 z-taps split 8 ways; 4-point comb per tap.
__device__ __forceinline__ void bZ_body(int tid, const float* __restrict__ b2a,
                                        float* __restrict__ out)
{
    const int NG = BATCH * 28 * 28 * 4;      // 12544 wave-groups
    int gid  = tid >> 6;
    int lane = tid & 63;
    float acc = 0.f;
    if (gid < NG) {
        int xh = gid & 3;
        int r1 = gid >> 2;
        int yo = r1 % 28;
        int r2 = r1 / 28;
        int zo = r2 % 28;
        int b  = r2 / 28;
        int sp = lane >> 3, xl = lane & 7;
        int xo = xh * 8 + xl;
        float s[5] = {0.f, 0.f, 0.f, 0.f, 0.f};
        if (xo < 28) {
            const float* base = b2a + (size_t)b * 72 * 4096 + (2 * yo) * 64 + 2 * xo;
            const float* p0 = base + (size_t)(2 * zo + sp) * 4096;
            const float* p1 = p0 + 8 * 4096;
            #pragma unroll
            for (int q = 0; q < 5; ++q) {
                const float* a0 = p0 + (size_t)q * N2Ae;
                const float* a1 = p1 + (size_t)q * N2Ae;
                s[q] = a0[0] + a0[9] + a0[576] + a0[585]
                     + a1[0] + a1[9] + a1[576] + a1[585];
            }
            if (sp < 2) {
                const float* p2 = p1 + 8 * 4096;
                #pragma unroll
                for (int q = 0; q < 5; ++q) {
                    const float* a2 = p2 + (size_t)q * N2Ae;
                    s[q] += a2[0] + a2[9] + a2[576] + a2[585];
                }
            }
        }
        #pragma unroll
        for (int off = 8; off < 64; off <<= 1) {
            #pragma unroll
            for (int q = 0; q < 5; ++q) s[q] += __shfl_xor(s[q], off, 64);
        }
        if (sp == 0 && xo < 28) acc = lncc_val(s, 1.0f / 5832.0f);
    }
    block_reduce_atomic(acc, 0.3f / 21952.0f, out);
}

// A: Z box-sum (9 planes, stride 1 in ez) + LNCC, sliding CHUNK=8
__device__ __forceinline__ void aZ_body(int tid, const float* __restrict__ b2a,
                                        float* __restrict__ out)
{
    const int total = BATCH * 8 * 64 * 64;           // 131072
    float acc = 0.f;
    if (tid < total) {
        int xo = tid & 63;
        int yo = (tid >> 6) & 63;
        int ch = (tid >> 12) & 7;
        int b  = tid >> 15;
        const int zo0 = ch * 8;
        const int OO = 64 * 64;
        const float* base = b2a + (size_t)b * 72 * OO + yo * 64 + xo;

        float s[5] = {0.f, 0.f, 0.f, 0.f, 0.f};
        #pragma unroll
        for (int j = 0; j < 9; ++j) {
            #pragma unroll
            for (int q = 0; q < 5; ++q)
                s[q] += base[(size_t)q * N2Ae + (zo0 + j) * OO];
        }
        acc += lncc_val(s, 1.0f / 729.0f);
        #pragma unroll
        for (int i = 1; i < 8; ++i) {
            #pragma unroll
            for (int q = 0; q < 5; ++q)
                s[q] += base[(size_t)q * N2Ae + (zo0 + i + 8) * OO]
                      - base[(size_t)q * N2Ae + (zo0 + i - 1) * OO];
            acc += lncc_val(s, 1.0f / 729.0f);
        }
    }
    block_reduce_atomic(acc, 0.1f / 262144.0f, out);
}

// C: Y-pass direct, tap-split TS=8
__device__ __forceinline__ void cY_body(int tid, const float* __restrict__ b1c,
                                        float* __restrict__ b2c)
{
    const int total = BATCH * DIM * 9 * 9 * 8;
    if (tid >= total) return;
    int sp   = tid & 7;
    int rest = tid >> 3;
    int xo = rest % 9;
    int yo = (rest / 9) % 9;
    int bz = rest / 81;
    const float* base = b1c + (size_t)bz * DIM * 9 + xo;

    float s[5] = {0.f, 0.f, 0.f, 0.f, 0.f};
    #pragma unroll
    for (int j = 0; j < 36; ++j) {
        if ((j & 7) == sp) {
            int y = 9 * yo + 2 * j;
            #pragma unroll
            for (int q = 0; q < 5; ++q) s[q] += base[(size_t)q * N1C + y * 9];
        }
    }
    #pragma unroll
    for (int off = 1; off < 8; off <<= 1) {
        #pragma unroll
        for (int q = 0; q < 5; ++q) s[q] += __shfl_xor(s[q], off, 64);
    }
    if (sp == 0) {
        float* ob = b2c + (size_t)bz * 81 + yo * 9 + xo;
        #pragma unroll
        for (int q = 0; q < 5; ++q) ob[(size_t)q * N2C] = s[q];
    }
}

constexpr int B_BZ = (BATCH * 28 * 28 * 4 * 64) / 256;   // 3136
constexpr int B_AZ = (BATCH * 8 * 64 * 64) / 256;        // 512
constexpr int B_CY = (BATCH * DIM * 9 * 9 * 8) / 256;    // 1458

__global__ __launch_bounds__(256) void k2(const float* __restrict__ b2a,
                                          const float* __restrict__ b1c,
                                          float* __restrict__ b2c,
                                          float* __restrict__ out)
{
    int blk = blockIdx.x;
    if (blk < B_BZ)             bZ_body(blk * 256 + threadIdx.x, b2a, out);
    else if (blk < B_BZ + B_AZ) aZ_body((blk - B_BZ) * 256 + threadIdx.x, b2a, out);
    else                        cY_body((blk - B_BZ - B_AZ) * 256 + threadIdx.x, b1c, b2c);
}

// ======================= k3: C Z-pass + LNCC ================================

__device__ __forceinline__ void cZ_body(int tid, const float* __restrict__ b2c,
                                        float* __restrict__ out)
{
    const int total = BATCH * 9 * 9 * 9 * 16;
    float acc = 0.f;
    if (tid < total) {
        int sp   = tid & 15;
        int rest = tid >> 4;
        int xo = rest % 9;
        int yo = (rest / 9) % 9;
        int zo = (rest / 81) % 9;
        int b  = rest / 729;
        const int OO = 81;
        const float* base = b2c + (size_t)b * DIM * OO + yo * 9 + xo;

        float s[5] = {0.f, 0.f, 0.f, 0.f, 0.f};
        #pragma unroll
        for (int j = 0; j < 36; ++j) {
            if ((j & 15) == sp) {
                int z = 9 * zo + 2 * j;
                #pragma unroll
                for (int q = 0; q < 5; ++q) s[q] += base[(size_t)q * N2C + z * OO];
            }
        }
        #pragma unroll
        for (int off = 1; off < 16; off <<= 1) {
            #pragma unroll
            for (int q = 0; q < 5; ++q) s[q] += __shfl_xor(s[q], off, 64);
        }
        if (sp == 0) acc = lncc_val(s, 1.0f / 46656.0f);
    }
    block_reduce_atomic(acc, 0.6f / 729.0f, out);
}

constexpr int B_CZ = (BATCH * 9 * 9 * 9 * 16 + 255) / 256;  // 183

__global__ __launch_bounds__(256) void k3(const float* __restrict__ b2c,
                                          float* __restrict__ out)
{
    cZ_body(blockIdx.x * 256 + threadIdx.x, b2c, out);
}

// ============================================================================
extern "C" void kernel_launch(void* const* d_in, const int* in_sizes, int n_in,
                              void* d_out, int out_size, void* d_ws, size_t ws_size,
                              hipStream_t stream) {
    const float* input  = (const float*)d_in[0];
    const float* target = (const float*)d_in[1];
    float* out = (float*)d_out;

    // workspace: b2a 23.6MB | b1c 14.9MB | b2c 0.93MB   (~39.5 MB)
    float* b2a = (float*)d_ws;
    float* b1c = b2a + (size_t)5 * N2Ae;
    float* b2c = b1c + (size_t)5 * N1C;

    k1<<<B_AXY + B_CX, 256, 0, stream>>>(input, target, b2a, b1c, out);
    k2<<<B_BZ + B_AZ + B_CY, 256, 0, stream>>>(b2a, b1c, b2c, out);
    k3<<<B_CZ, 256, 0, stream>>>(b2c, out);
}

// Round 7
// 88.161 us; speedup vs baseline: 2.3079x; 1.3407x over previous
//
#include <hip/hip_runtime.h>

// LNCC multi-scale loss, fp32, (4,1,144,144,144) -> scalar.
// A(K=9,ST=2), B(K=18,ST=4): all taps on even coords -> even-grid volume.
//   A = 9^3 box stride 1 on even grid; B = 18^3 = eight 9^3 boxes =>
//   B-XY = 4 adds over A's XY sums; B-Z from compact b2b.
// C(K=36,ST=9): separable 3-pass.
// NO same-address atomics: reducing blocks write partial[blockIdx]; k4 does
// the weighted final sum (and writes out[0] = 4 - total).
// k1: A-XY + C-X (one input sweep)
// k2: A-Z+LNCC->pA | B-XY (b2a->b2b) | C-Y (b1c->b2c)
// k3: B-Z+LNCC->pB | C-Z+LNCC->pC
// k4: weighted reduce of pA,pB,pC -> out

constexpr int BATCH = 4;
constexpr int DIM   = 144;
constexpr int NROWS = BATCH * DIM * DIM;        // 82944
constexpr float EPS = 1e-5f;

constexpr int N1C  = NROWS * 9;                 //   746,496 (C X-out)
constexpr int N2Ae = BATCH * 72 * 64 * 64;      // 1,179,648 (A XY-out)
constexpr int N2Be = BATCH * 72 * 28 * 28;      //   225,792 (B XY-out)
constexpr int N2C  = BATCH * DIM * 9 * 9;       //    46,656 (C Y-out)

// ======================= shared device helpers ==============================

__device__ __forceinline__ float lncc_val(const float s[5], float inv_numel) {
    float cross = s[4] - s[0] * s[1] * inv_numel;
    float ivar  = s[2] - s[0] * s[0] * inv_numel;
    float tvar  = s[3] - s[1] * s[1] * inv_numel;
    return (cross * cross) / (ivar * tvar + EPS);
}

// per-block reduce -> partial[slot]  (no atomics)
__device__ __forceinline__ void block_reduce_store(float acc, float* slot) {
    #pragma unroll
    for (int off = 32; off > 0; off >>= 1) acc += __shfl_down(acc, off, 64);
    __shared__ float sm[4];
    int lane = threadIdx.x & 63, wid = threadIdx.x >> 6;
    if (lane == 0) sm[wid] = acc;
    __syncthreads();
    if (threadIdx.x == 0) *slot = sm[0] + sm[1] + sm[2] + sm[3];
}

// ======================= k1 bodies ==========================================
// aXY: one even-z plane, one 16-wide xo chunk. X-phase taps read global
// directly (L1/L2-hot); X-sums in padded LDS xs[72][81]; Y-phase sliding.

__device__ void aXY_body(int blk, const float* __restrict__ in,
                         const float* __restrict__ tg,
                         float* __restrict__ b2a, float* xs)
{
    const int p  = blk >> 2;            // b*72 + ez
    const int c  = blk & 3;
    const int b  = p / 72;
    const int ez = p % 72;
    const int xo0 = c * 16;
    const size_t gpl = (size_t)(b * DIM + 2 * ez) * (DIM * DIM);
    const int t = threadIdx.x;

    for (int i = t; i < 72 * 16; i += 256) {
        int yp = i >> 4, dx = i & 15;
        size_t g = gpl + (size_t)(2 * yp) * DIM + 2 * (size_t)(xo0 + dx);
        const float* ga = in + g;
        const float* gb = tg + g;
        float s0 = 0.f, s1 = 0.f, s2 = 0.f, s3 = 0.f, s4 = 0.f;
        #pragma unroll
        for (int j = 0; j < 9; ++j) {
            float a = ga[2 * j], bb = gb[2 * j];
            s0 += a; s1 += bb; s2 += a * a; s3 += bb * bb; s4 += a * bb;
        }
        float* d = &xs[yp * 81 + dx];
        d[0] = s0; d[16] = s1; d[32] = s2; d[48] = s3; d[64] = s4;
    }
    __syncthreads();

    for (int it = t; it < 320; it += 256) {
        int dx = it & 15;
        int q  = (it >> 4) % 5;
        int ch = it / 80;
        int yo0 = ch << 4;
        const float* xp = &xs[q * 16 + dx];
        float s = 0.f;
        #pragma unroll
        for (int j = 0; j < 9; ++j) s += xp[(yo0 + j) * 81];
        float* ob = b2a + (size_t)q * N2Ae + ((size_t)p * 64 + yo0) * 64 + xo0 + dx;
        ob[0] = s;
        #pragma unroll
        for (int i2 = 1; i2 < 16; ++i2) {
            s += xp[(yo0 + i2 + 8) * 81] - xp[(yo0 + i2 - 1) * 81];
            ob[(size_t)i2 * 64] = s;
        }
    }
}

// cX: 12 rows staged in LDS, 2-way tap-split
constexpr int CXROWS = 12;

__device__ void cX_body(int blk, const float* __restrict__ in,
                        const float* __restrict__ tg,
                        float* __restrict__ b1c, float* sm)
{
    float* la = sm;                     // [12][145]
    float* lb = sm + CXROWS * 145;
    const int t = threadIdx.x;
    const int row0 = blk * CXROWS;
    const float* gin = in + (size_t)row0 * DIM;
    const float* gtg = tg + (size_t)row0 * DIM;
    for (int i = t; i < CXROWS * DIM; i += 256) {
        int rr = i / DIM, cc = i % DIM;
        la[rr * 145 + cc] = gin[i];
        lb[rr * 145 + cc] = gtg[i];
    }
    __syncthreads();
    if (t < CXROWS * 18) {
        int rr  = t / 18;
        int rem = t % 18;
        int xo = rem >> 1, sp = rem & 1;
        const float* pa = &la[rr * 145 + xo * 9 + 2 * sp];
        const float* pb = &lb[rr * 145 + xo * 9 + 2 * sp];
        float s0 = 0.f, s1 = 0.f, s2 = 0.f, s3 = 0.f, s4 = 0.f;
        #pragma unroll
        for (int jj = 0; jj < 18; ++jj) {
            float a = pa[4 * jj], b = pb[4 * jj];
            s0 += a; s1 += b; s2 += a * a; s3 += b * b; s4 += a * b;
        }
        s0 += __shfl_xor(s0, 1, 64);
        s1 += __shfl_xor(s1, 1, 64);
        s2 += __shfl_xor(s2, 1, 64);
        s3 += __shfl_xor(s3, 1, 64);
        s4 += __shfl_xor(s4, 1, 64);
        if (sp == 0) {
            int o = (row0 + rr) * 9 + xo;
            b1c[o] = s0; b1c[N1C + o] = s1; b1c[2 * N1C + o] = s2;
            b1c[3 * N1C + o] = s3; b1c[4 * N1C + o] = s4;
        }
    }
}

constexpr int B_AXY = BATCH * 72 * 4;        // 1152
constexpr int B_CX  = NROWS / CXROWS;        // 6912
constexpr int SM1   = 72 * 81;               // 5832 floats (23.3 KB)

__global__ __launch_bounds__(256) void k1(const float* __restrict__ in,
                                          const float* __restrict__ tg,
                                          float* __restrict__ b2a,
                                          float* __restrict__ b1c)
{
    __shared__ float smem[SM1];
    int blk = blockIdx.x;
    if (blk < B_AXY) aXY_body(blk, in, tg, b2a, smem);
    else             cX_body(blk - B_AXY, in, tg, b1c, smem);
}

// ======================= k2 bodies ==========================================

// A: Z box-sum (9 planes, stride 1 in ez) + LNCC, sliding CHUNK=8 -> pA[blk]
__device__ __forceinline__ void aZ_body(int blk, const float* __restrict__ b2a,
                                        float* __restrict__ pA)
{
    int tid = blk * 256 + threadIdx.x;
    float acc = 0.f;
    {
        int xo = tid & 63;
        int yo = (tid >> 6) & 63;
        int ch = (tid >> 12) & 7;
        int b  = tid >> 15;
        const int zo0 = ch * 8;
        const int OO = 64 * 64;
        const float* base = b2a + (size_t)b * 72 * OO + yo * 64 + xo;

        float s[5] = {0.f, 0.f, 0.f, 0.f, 0.f};
        #pragma unroll
        for (int j = 0; j < 9; ++j) {
            #pragma unroll
            for (int q = 0; q < 5; ++q)
                s[q] += base[(size_t)q * N2Ae + (zo0 + j) * OO];
        }
        acc += lncc_val(s, 1.0f / 729.0f);
        #pragma unroll
        for (int i = 1; i < 8; ++i) {
            #pragma unroll
            for (int q = 0; q < 5; ++q)
                s[q] += base[(size_t)q * N2Ae + (zo0 + i + 8) * OO]
                      - base[(size_t)q * N2Ae + (zo0 + i - 1) * OO];
            acc += lncc_val(s, 1.0f / 729.0f);
        }
    }
    block_reduce_store(acc, pA + blk);
}

// B XY from A's XY: 18x18 window = four 9x9 windows (coalesced-ish, tiny)
__device__ __forceinline__ void bXY_body(int tid, const float* __restrict__ b2a,
                                         float* __restrict__ b2b)
{
    const int total = BATCH * 72 * 28 * 28;          // 225792
    if (tid >= total) return;
    int xo = tid % 28;
    int yo = (tid / 28) % 28;
    int p  = tid / 784;
    const float* ib = b2a + (size_t)p * 4096;
    float* ob = b2b + (size_t)p * 784 + yo * 28 + xo;
    int r0 = (2 * yo) * 64 + 2 * xo;
    #pragma unroll
    for (int q = 0; q < 5; ++q) {
        const float* pq = ib + (size_t)q * N2Ae;
        ob[(size_t)q * N2Be] =
            pq[r0] + pq[r0 + 9] + pq[r0 + 9 * 64] + pq[r0 + 9 * 64 + 9];
    }
}

// C: Y-pass direct, tap-split TS=8
__device__ __forceinline__ void cY_body(int tid, const float* __restrict__ b1c,
                                        float* __restrict__ b2c)
{
    const int total = BATCH * DIM * 9 * 9 * 8;
    if (tid >= total) return;
    int sp   = tid & 7;
    int rest = tid >> 3;
    int xo = rest % 9;
    int yo = (rest / 9) % 9;
    int bz = rest / 81;
    const float* base = b1c + (size_t)bz * DIM * 9 + xo;

    float s[5] = {0.f, 0.f, 0.f, 0.f, 0.f};
    #pragma unroll
    for (int j = 0; j < 36; ++j) {
        if ((j & 7) == sp) {
            int y = 9 * yo + 2 * j;
            #pragma unroll
            for (int q = 0; q < 5; ++q) s[q] += base[(size_t)q * N1C + y * 9];
        }
    }
    #pragma unroll
    for (int off = 1; off < 8; off <<= 1) {
        #pragma unroll
        for (int q = 0; q < 5; ++q) s[q] += __shfl_xor(s[q], off, 64);
    }
    if (sp == 0) {
        float* ob = b2c + (size_t)bz * 81 + yo * 9 + xo;
        #pragma unroll
        for (int q = 0; q < 5; ++q) ob[(size_t)q * N2C] = s[q];
    }
}

constexpr int B_AZ  = (BATCH * 8 * 64 * 64) / 256;       // 512
constexpr int B_BXY = (BATCH * 72 * 28 * 28) / 256;      // 882
constexpr int B_CY  = (BATCH * DIM * 9 * 9 * 8) / 256;   // 1458

__global__ __launch_bounds__(256) void k2(const float* __restrict__ b2a,
                                          const float* __restrict__ b1c,
                                          float* __restrict__ b2b,
                                          float* __restrict__ b2c,
                                          float* __restrict__ pA)
{
    int blk = blockIdx.x;
    if (blk < B_AZ)              aZ_body(blk, b2a, pA);
    else if (blk < B_AZ + B_BXY) bXY_body((blk - B_AZ) * 256 + threadIdx.x, b2a, b2b);
    else                         cY_body((blk - B_AZ - B_BXY) * 256 + threadIdx.x, b1c, b2c);
}

// ======================= k3 bodies ==========================================

// B: Z box-sum (18 even-z planes of b2b, base 2*zo) + LNCC, TS=8 -> pB[blk]
__device__ __forceinline__ void bZ_body(int blk, const float* __restrict__ b2b,
                                        float* __restrict__ pB)
{
    int tid = blk * 256 + threadIdx.x;
    float acc = 0.f;
    {
        int sp   = tid & 7;
        int rest = tid >> 3;
        int xo = rest % 28;
        int yo = (rest / 28) % 28;
        int zo = (rest / 784) % 28;
        int b  = rest / 21952;
        const int OO = 784;
        const float* base = b2b + (size_t)b * 72 * OO + yo * 28 + xo;

        float s[5] = {0.f, 0.f, 0.f, 0.f, 0.f};
        #pragma unroll
        for (int j = 0; j < 18; ++j) {
            if ((j & 7) == sp) {
                #pragma unroll
                for (int q = 0; q < 5; ++q)
                    s[q] += base[(size_t)q * N2Be + (2 * zo + j) * OO];
            }
        }
        #pragma unroll
        for (int off = 1; off < 8; off <<= 1) {
            #pragma unroll
            for (int q = 0; q < 5; ++q) s[q] += __shfl_xor(s[q], off, 64);
        }
        if (sp == 0) acc = lncc_val(s, 1.0f / 5832.0f);
    }
    block_reduce_store(acc, pB + blk);
}

// C: Z-pass + LNCC, TS=16 -> pC[blk]
__device__ __forceinline__ void cZ_body(int blk, const float* __restrict__ b2c,
                                        float* __restrict__ pC)
{
    int tid = blk * 256 + threadIdx.x;
    const int total = BATCH * 9 * 9 * 9 * 16;
    float acc = 0.f;
    if (tid < total) {
        int sp   = tid & 15;
        int rest = tid >> 4;
        int xo = rest % 9;
        int yo = (rest / 9) % 9;
        int zo = (rest / 81) % 9;
        int b  = rest / 729;
        const int OO = 81;
        const float* base = b2c + (size_t)b * DIM * OO + yo * 9 + xo;

        float s[5] = {0.f, 0.f, 0.f, 0.f, 0.f};
        #pragma unroll
        for (int j = 0; j < 36; ++j) {
            if ((j & 15) == sp) {
                int z = 9 * zo + 2 * j;
                #pragma unroll
                for (int q = 0; q < 5; ++q) s[q] += base[(size_t)q * N2C + z * OO];
            }
        }
        #pragma unroll
        for (int off = 1; off < 16; off <<= 1) {
            #pragma unroll
            for (int q = 0; q < 5; ++q) s[q] += __shfl_xor(s[q], off, 64);
        }
        if (sp == 0) acc = lncc_val(s, 1.0f / 46656.0f);
    }
    block_reduce_store(acc, pC + blk);
}

constexpr int B_BZ = (BATCH * 28 * 28 * 28 * 8) / 256;     // 2744
constexpr int B_CZ = (BATCH * 9 * 9 * 9 * 16 + 255) / 256; // 183

__global__ __launch_bounds__(256) void k3(const float* __restrict__ b2b,
                                          const float* __restrict__ b2c,
                                          float* __restrict__ pB,
                                          float* __restrict__ pC)
{
    int blk = blockIdx.x;
    if (blk < B_BZ) bZ_body(blk, b2b, pB);
    else            cZ_body(blk - B_BZ, b2c, pC);
}

// ======================= k4: weighted final reduce ==========================

__global__ __launch_bounds__(256) void k4(const float* __restrict__ pA,
                                          const float* __restrict__ pB,
                                          const float* __restrict__ pC,
                                          float* __restrict__ out)
{
    const int t = threadIdx.x;
    float sA = 0.f, sB = 0.f, sC = 0.f;
    for (int i = t; i < B_AZ; i += 256) sA += pA[i];
    for (int i = t; i < B_BZ; i += 256) sB += pB[i];
    for (int i = t; i < B_CZ; i += 256) sC += pC[i];
    float s = (0.1f / 262144.0f) * sA + (0.3f / 21952.0f) * sB
            + (0.6f / 729.0f) * sC;
    #pragma unroll
    for (int off = 32; off > 0; off >>= 1) s += __shfl_down(s, off, 64);
    __shared__ float sm[4];
    int lane = t & 63, wid = t >> 6;
    if (lane == 0) sm[wid] = s;
    __syncthreads();
    if (t == 0) out[0] = 4.0f - (sm[0] + sm[1] + sm[2] + sm[3]);
}

// ============================================================================
extern "C" void kernel_launch(void* const* d_in, const int* in_sizes, int n_in,
                              void* d_out, int out_size, void* d_ws, size_t ws_size,
                              hipStream_t stream) {
    const float* input  = (const float*)d_in[0];
    const float* target = (const float*)d_in[1];
    float* out = (float*)d_out;

    // ws: b2a 23.6MB | b1c 14.9MB | b2b 4.5MB | b2c 0.93MB | partials ~14KB
    float* b2a = (float*)d_ws;
    float* b1c = b2a + (size_t)5 * N2Ae;
    float* b2b = b1c + (size_t)5 * N1C;
    float* b2c = b2b + (size_t)5 * N2Be;
    float* pA  = b2c + (size_t)5 * N2C;
    float* pB  = pA + B_AZ;
    float* pC  = pB + B_BZ;

    k1<<<B_AXY + B_CX, 256, 0, stream>>>(input, target, b2a, b1c);
    k2<<<B_AZ + B_BXY + B_CY, 256, 0, stream>>>(b2a, b1c, b2b, b2c, pA);
    k3<<<B_BZ + B_CZ, 256, 0, stream>>>(b2b, b2c, pB, pC);
    k4<<<1, 256, 0, stream>>>(pA, pB, pC, out);
}